// Round 1
// baseline (962.337 us; speedup 1.0000x reference)
//
#include <hip/hip_runtime.h>
#include <math.h>

// Problem constants
#define N_  4
#define H_  96
#define W_  96
#define HW  9216          // H*W
#define NHW 36864         // N*H*W
#define O_  128           // output channels of both convs

// ---------------------------------------------------------------------------
// wT[ck*O + o] = w[o*CK + ck]   (GEMM B-matrix layout, coalesced over o)
__global__ void transpose_w_kernel(const float* __restrict__ w, float* __restrict__ wT,
                                   int O, int CK) {
  int i = blockIdx.x * 256 + threadIdx.x;
  if (i >= O * CK) return;
  int ck = i / O, o = i % O;
  wT[i] = w[o * CK + ck];
}

// owT[(c*9+kk)*28 + j] = off_w[(j*C + c)*9 + kk], j padded 27->28 for float4
__global__ void transpose_ow_kernel(const float* __restrict__ ow, float* __restrict__ owT,
                                    int C) {
  int i = blockIdx.x * 256 + threadIdx.x;
  if (i >= C * 9 * 28) return;
  int j = i % 28, ckk = i / 28;
  int kk = ckk % 9, c = ckk / 9;
  owT[i] = (j < 27) ? ow[(j * C + c) * 9 + kk] : 0.f;
}

// ---------------------------------------------------------------------------
// Offset conv (27-channel 3x3, pad 1). Thread per pixel, 28 accumulators.
// C is split 4-ways across blocks (occupancy); partials reduced later.
__global__ __launch_bounds__(256) void offset_conv_kernel(
    const float* __restrict__ x, const float* __restrict__ owT,
    const float* __restrict__ ob, float* __restrict__ part, int C) {
  int t = blockIdx.x * 256 + threadIdx.x;   // over 4*NHW
  int pixel = t % NHW;
  int s = t / NHW;                          // c-split id 0..3
  int n = pixel / HW, rem = pixel % HW;
  int h = rem / W_, w = rem % W_;
  int cq = C >> 2;
  int c0 = s * cq;
  float acc[28];
#pragma unroll
  for (int j = 0; j < 28; ++j) acc[j] = 0.f;
  if (s == 0) {
#pragma unroll
    for (int j = 0; j < 27; ++j) acc[j] = ob[j];
  }
  const float* xn = x + (size_t)n * C * HW;
  for (int c = c0; c < c0 + cq; ++c) {
    const float* xp = xn + (size_t)c * HW;
    const float* wc = owT + (size_t)c * 9 * 28;
#pragma unroll
    for (int ky = 0; ky < 3; ++ky) {
      int y = h + ky - 1;
      bool vy = (y >= 0 && y < H_);
#pragma unroll
      for (int kx = 0; kx < 3; ++kx) {
        int xx = w + kx - 1;
        float xv = (vy && xx >= 0 && xx < W_) ? xp[y * W_ + xx] : 0.f;
        const float4* wp = reinterpret_cast<const float4*>(wc + (ky * 3 + kx) * 28);
#pragma unroll
        for (int q = 0; q < 7; ++q) {
          float4 wv = wp[q];
          acc[q * 4 + 0] = fmaf(xv, wv.x, acc[q * 4 + 0]);
          acc[q * 4 + 1] = fmaf(xv, wv.y, acc[q * 4 + 1]);
          acc[q * 4 + 2] = fmaf(xv, wv.z, acc[q * 4 + 2]);
          acc[q * 4 + 3] = fmaf(xv, wv.w, acc[q * 4 + 3]);
        }
      }
    }
  }
  float* dst = part + (size_t)s * (N_ * 27 * HW) + (size_t)n * 27 * HW + rem;
#pragma unroll
  for (int j = 0; j < 27; ++j) dst[(size_t)j * HW] = acc[j];
}

__global__ void reduce_off_kernel(const float* __restrict__ part, float* __restrict__ off) {
  int i = blockIdx.x * 256 + threadIdx.x;   // float4 index over N*27*HW/4
  const float4* p = reinterpret_cast<const float4*>(part);
  const int st = N_ * 27 * HW / 4;
  float4 a = p[i], b = p[i + st], c = p[i + 2 * st], d = p[i + 3 * st];
  float4 r;
  r.x = a.x + b.x + c.x + d.x;
  r.y = a.y + b.y + c.y + d.y;
  r.z = a.z + b.z + c.z + d.z;
  r.w = a.w + b.w + c.w + d.w;
  reinterpret_cast<float4*>(off)[i] = r;
}

// ---------------------------------------------------------------------------
// Deformable sampling + contraction as tiled GEMM.
// Block: 256 threads, 64 pixels (M) x 128 outputs (N), K = C*9.
// Thread tile 4x8.  s[p][ck] staged in LDS per 32-wide K chunk.
template <int C>
__global__ __launch_bounds__(256) void deform_gemm_kernel(
    const float* __restrict__ x, const float* __restrict__ off,
    const float* __restrict__ wT, float* __restrict__ y) {
  constexpr int CK = C * 9;
  __shared__ float swgt[64][9][4];
  __shared__ int   sidx[64][9][4];
  __shared__ float s_s[32][64];
  __shared__ float s_w[32][128];

  int tid = threadIdx.x;
  int pix0 = blockIdx.x * 64;          // 576 blocks; never crosses n boundary
  int n = pix0 / HW;
  int rem0 = pix0 % HW;
  const float* xn = x + (size_t)n * C * HW;
  const float* offn = off + (size_t)n * 27 * HW;

  // Stage A: bilinear metadata for 64 pixels x 9 taps
  for (int t = tid; t < 576; t += 256) {
    int p = t / 9, k = t % 9;
    int rem = rem0 + p;
    int h = rem / W_, w = rem % W_;
    float dy = offn[(size_t)(2 * k) * HW + rem];
    float dx = offn[(size_t)(2 * k + 1) * HW + rem];
    float mo = offn[(size_t)(18 + k) * HW + rem];
    float m = 1.f / (1.f + __expf(-mo));
    float py = dy + (float)(k / 3 - 1) + (float)h;
    float px = dx + (float)(k % 3 - 1) + (float)w;
    float fy = floorf(py), fx = floorf(px);
    int y0 = (int)fy, x0 = (int)fx;
    float ly = py - fy, lx = px - fx;
    float wbl[4] = {(1.f - ly) * (1.f - lx), (1.f - ly) * lx,
                    ly * (1.f - lx), ly * lx};
#pragma unroll
    for (int jj = 0; jj < 4; ++jj) {
      int yy = y0 + (jj >> 1);
      int xx = x0 + (jj & 1);
      bool v = (yy >= 0 && yy < H_ && xx >= 0 && xx < W_);
      int yc = min(max(yy, 0), H_ - 1), xc = min(max(xx, 0), W_ - 1);
      sidx[p][k][jj] = yc * W_ + xc;
      swgt[p][k][jj] = v ? wbl[jj] * m : 0.f;
    }
  }
  __syncthreads();

  float acc[4][8];
#pragma unroll
  for (int a = 0; a < 4; ++a)
#pragma unroll
    for (int b = 0; b < 8; ++b) acc[a][b] = 0.f;

  int ty = tid / 16;   // pixel group: pixels ty*4 .. ty*4+3
  int tx = tid % 16;   // output group: o = tx*8 .. tx*8+7

  for (int ck0 = 0; ck0 < CK; ck0 += 32) {
    // fill s_s: 32 ck x 64 pixels; thread fills 8 consecutive pixels of one ck
    {
      int ckk = tid >> 3;
      int pbase = (tid & 7) << 3;
      int ck = ck0 + ckk;
      int c = ck / 9, k = ck % 9;
      const float* xp = xn + (size_t)c * HW;
#pragma unroll
      for (int i = 0; i < 8; ++i) {
        int p = pbase + i;
        float s = swgt[p][k][0] * xp[sidx[p][k][0]]
                + swgt[p][k][1] * xp[sidx[p][k][1]]
                + swgt[p][k][2] * xp[sidx[p][k][2]]
                + swgt[p][k][3] * xp[sidx[p][k][3]];
        s_s[ckk][p] = s;
      }
    }
    // fill s_w: 32 ck x 128 outputs, coalesced float4
    {
      const float4* wsrc = reinterpret_cast<const float4*>(wT + (size_t)ck0 * O_);
      float4* wdst = reinterpret_cast<float4*>(&s_w[0][0]);
#pragma unroll
      for (int i = 0; i < 4; ++i) wdst[tid + 256 * i] = wsrc[tid + 256 * i];
    }
    __syncthreads();
#pragma unroll 8
    for (int ckk = 0; ckk < 32; ++ckk) {
      float a[4], b[8];
      *reinterpret_cast<float4*>(a) = *reinterpret_cast<const float4*>(&s_s[ckk][ty * 4]);
      *reinterpret_cast<float4*>(b) = *reinterpret_cast<const float4*>(&s_w[ckk][tx * 8]);
      *reinterpret_cast<float4*>(b + 4) = *reinterpret_cast<const float4*>(&s_w[ckk][tx * 8 + 4]);
#pragma unroll
      for (int pp = 0; pp < 4; ++pp)
#pragma unroll
        for (int oo = 0; oo < 8; ++oo)
          acc[pp][oo] = fmaf(a[pp], b[oo], acc[pp][oo]);
    }
    __syncthreads();
  }

  // epilogue: y[n][o][rem0 + ty*4 + pp]
#pragma unroll
  for (int oo = 0; oo < 8; ++oo) {
    int o = tx * 8 + oo;
    float* dst = y + ((size_t)n * O_ + o) * HW + rem0 + ty * 4;
    float4 v = make_float4(acc[0][oo], acc[1][oo], acc[2][oo], acc[3][oo]);
    *reinterpret_cast<float4*>(dst) = v;
  }
}

// ---------------------------------------------------------------------------
// BN stats: block per (n,c); accumulate sum/sumsq into stats[c], stats[128+c]
__global__ void bn_stats_kernel(const float* __restrict__ y, float* __restrict__ stats) {
  int blk = blockIdx.x;           // n*128 + c
  int c = blk & 127;
  const float4* p = reinterpret_cast<const float4*>(y + (size_t)blk * HW);
  float s = 0.f, s2 = 0.f;
  for (int i = threadIdx.x; i < HW / 4; i += 256) {
    float4 v = p[i];
    s += v.x + v.y + v.z + v.w;
    s2 += v.x * v.x + v.y * v.y + v.z * v.z + v.w * v.w;
  }
#pragma unroll
  for (int off = 32; off; off >>= 1) {
    s += __shfl_down(s, off);
    s2 += __shfl_down(s2, off);
  }
  __shared__ float red[8];
  int wave = threadIdx.x >> 6, lane = threadIdx.x & 63;
  if (lane == 0) { red[wave] = s; red[4 + wave] = s2; }
  __syncthreads();
  if (threadIdx.x == 0) {
    float ts = red[0] + red[1] + red[2] + red[3];
    float ts2 = red[4] + red[5] + red[6] + red[7];
    atomicAdd(&stats[c], ts);
    atomicAdd(&stats[128 + c], ts2);
  }
}

__global__ void bn_apply_kernel(const float* __restrict__ y, const float* __restrict__ stats,
                                const float* __restrict__ gamma, const float* __restrict__ beta,
                                float* __restrict__ out) {
  int i = blockIdx.x * 256 + threadIdx.x;     // float4 index
  int c = (i / (HW / 4)) & 127;
  float mu = stats[c] * (1.f / (float)NHW);
  float var = stats[128 + c] * (1.f / (float)NHW) - mu * mu;
  float sc = rsqrtf(var + 1e-5f) * gamma[c];
  float sh = beta[c] - mu * sc;
  float4 v = reinterpret_cast<const float4*>(y)[i];
  v.x = fmaxf(fmaf(v.x, sc, sh), 0.f);
  v.y = fmaxf(fmaf(v.y, sc, sh), 0.f);
  v.z = fmaxf(fmaf(v.z, sc, sh), 0.f);
  v.w = fmaxf(fmaf(v.w, sc, sh), 0.f);
  reinterpret_cast<float4*>(out)[i] = v;
}

// ---------------------------------------------------------------------------
extern "C" void kernel_launch(void* const* d_in, const int* in_sizes, int n_in,
                              void* d_out, int out_size, void* d_ws, size_t ws_size,
                              hipStream_t stream) {
  const float* x      = (const float*)d_in[0];
  const float* w1     = (const float*)d_in[1];
  const float* off_w1 = (const float*)d_in[2];
  const float* off_b1 = (const float*)d_in[3];
  const float* gamma1 = (const float*)d_in[4];
  const float* beta1  = (const float*)d_in[5];
  const float* w2     = (const float*)d_in[6];
  const float* off_w2 = (const float*)d_in[7];
  const float* off_b2 = (const float*)d_in[8];
  const float* gamma2 = (const float*)d_in[9];
  const float* beta2  = (const float*)d_in[10];
  float* out = (float*)d_out;

  // workspace layout (floats)
  float* ws    = (float*)d_ws;
  float* off   = ws;                               // 995328
  float* part  = off + 995328;                     // 4*995328 = 3981312
  float* h     = part + 3981312;                   // 4718592
  float* wT1   = h + 4718592;                      // 73728
  float* wT2   = wT1 + 73728;                      // 147456
  float* owT1  = wT2 + 147456;                     // 16128
  float* owT2  = owT1 + 16128;                     // 32256
  float* stats = owT2 + 32256;                     // 512 (layer1: 0..255, layer2: 256..511)
  float* y     = out;                              // pre-BN conv output lives in d_out

  // weight transposes
  transpose_w_kernel<<<288, 256, 0, stream>>>(w1, wT1, 128, 576);
  transpose_w_kernel<<<576, 256, 0, stream>>>(w2, wT2, 128, 1152);
  transpose_ow_kernel<<<63, 256, 0, stream>>>(off_w1, owT1, 64);
  transpose_ow_kernel<<<126, 256, 0, stream>>>(off_w2, owT2, 128);
  hipMemsetAsync(stats, 0, 512 * sizeof(float), stream);

  // ---- layer 1 ----
  offset_conv_kernel<<<576, 256, 0, stream>>>(x, owT1, off_b1, part, 64);
  reduce_off_kernel<<<972, 256, 0, stream>>>(part, off);
  deform_gemm_kernel<64><<<576, 256, 0, stream>>>(x, off, wT1, y);
  bn_stats_kernel<<<512, 256, 0, stream>>>(y, stats);
  bn_apply_kernel<<<4608, 256, 0, stream>>>(y, stats, gamma1, beta1, h);

  // ---- layer 2 ----
  offset_conv_kernel<<<576, 256, 0, stream>>>(h, owT2, off_b2, part, 128);
  reduce_off_kernel<<<972, 256, 0, stream>>>(part, off);
  deform_gemm_kernel<128><<<576, 256, 0, stream>>>(h, off, wT2, y);
  bn_stats_kernel<<<512, 256, 0, stream>>>(y, stats + 256);
  bn_apply_kernel<<<4608, 256, 0, stream>>>(y, stats + 256, gamma2, beta2, out);
}

// Round 6
// 820.730 us; speedup vs baseline: 1.1725x; 1.1725x over previous
//
#include <hip/hip_runtime.h>
#include <math.h>

#define N_  4
#define H_  96
#define W_  96
#define HW  9216          // H*W
#define NHW 36864         // N*H*W
#define O_  128

typedef unsigned short ushort_t;
typedef __attribute__((ext_vector_type(8))) short bf16x8;
typedef __attribute__((ext_vector_type(4))) float f32x4;
typedef __attribute__((ext_vector_type(8))) unsigned short u16x8;

__device__ __forceinline__ float bf2f(ushort_t u) {
  return __uint_as_float(((unsigned int)u) << 16);
}
__device__ __forceinline__ ushort_t f2bf(float f) {
  unsigned int u = __float_as_uint(f);
  u += 0x7fffu + ((u >> 16) & 1u);           // RNE
  return (ushort_t)(u >> 16);
}

// ---------------------------------------------------------------------------
__global__ void f32_to_bf16_kernel(const float* __restrict__ in,
                                   ushort_t* __restrict__ out, int n8) {
  int i = blockIdx.x * 256 + threadIdx.x;
  if (i >= n8) return;
  const float4* p = reinterpret_cast<const float4*>(in) + (size_t)i * 2;
  float4 a = p[0], b = p[1];
  u16x8 r;
  r[0] = f2bf(a.x); r[1] = f2bf(a.y); r[2] = f2bf(a.z); r[3] = f2bf(a.w);
  r[4] = f2bf(b.x); r[5] = f2bf(b.y); r[6] = f2bf(b.z); r[7] = f2bf(b.w);
  reinterpret_cast<u16x8*>(out)[i] = r;
}

// wB[o][kk*C+c] = bf16(w[o][c][kk])   (B^T layout for MFMA, k contiguous)
__global__ void transpose_w_kernel(const float* __restrict__ w,
                                   ushort_t* __restrict__ wB, int C) {
  int K = C * 9;
  int i = blockIdx.x * 256 + threadIdx.x;
  if (i >= 128 * K) return;
  int o = i / K, r = i % K;
  int kk = r / C, c = r % C;
  wB[i] = f2bf(w[(o * C + c) * 9 + kk]);
}

// owT[(c*9+kk)*28 + j] = off_w[(j*C + c)*9 + kk], j padded 27->28
__global__ void transpose_ow_kernel(const float* __restrict__ ow,
                                    float* __restrict__ owT, int C) {
  int i = blockIdx.x * 256 + threadIdx.x;
  if (i >= C * 9 * 28) return;
  int j = i % 28, ckk = i / 28;
  int kk = ckk % 9, c = ckk / 9;
  owT[i] = (j < 27) ? ow[(j * C + c) * 9 + kk] : 0.f;
}

__global__ void bias_fill_kernel(float* __restrict__ off, const float* __restrict__ ob) {
  int i = blockIdx.x * 256 + threadIdx.x;
  if (i >= N_ * 27 * HW) return;
  off[i] = ob[(i / HW) % 27];
}

// ---------------------------------------------------------------------------
// Offset conv: bf16 input [n][c][hw], 3x3 pad 1, 27 out channels.
// Thread per pixel, C split 4-ways; partials accumulated via atomicAdd.
__global__ __launch_bounds__(256) void offset_conv_kernel(
    const ushort_t* __restrict__ xb, const float* __restrict__ owT,
    float* __restrict__ off, int C) {
  int t = blockIdx.x * 256 + threadIdx.x;   // 4*NHW
  int pixel = t % NHW;
  int s4 = t / NHW;
  int n = pixel / HW, rem = pixel % HW;
  int h = rem / W_, w = rem % W_;
  int cq = C >> 2;
  int c0 = s4 * cq;
  float acc[28];
#pragma unroll
  for (int j = 0; j < 28; ++j) acc[j] = 0.f;
  const ushort_t* xn = xb + (size_t)n * C * HW;
  for (int c = c0; c < c0 + cq; ++c) {
    const ushort_t* xp = xn + (size_t)c * HW;
    const float* wc = owT + (size_t)c * 9 * 28;
#pragma unroll
    for (int ky = 0; ky < 3; ++ky) {
      int y = h + ky - 1;
      bool vy = (y >= 0 && y < H_);
#pragma unroll
      for (int kx = 0; kx < 3; ++kx) {
        int xx = w + kx - 1;
        float xv = (vy && xx >= 0 && xx < W_) ? bf2f(xp[y * W_ + xx]) : 0.f;
        const float4* wp = reinterpret_cast<const float4*>(wc + (ky * 3 + kx) * 28);
#pragma unroll
        for (int q = 0; q < 7; ++q) {
          float4 wv = wp[q];
          acc[q * 4 + 0] = fmaf(xv, wv.x, acc[q * 4 + 0]);
          acc[q * 4 + 1] = fmaf(xv, wv.y, acc[q * 4 + 1]);
          acc[q * 4 + 2] = fmaf(xv, wv.z, acc[q * 4 + 2]);
          acc[q * 4 + 3] = fmaf(xv, wv.w, acc[q * 4 + 3]);
        }
      }
    }
  }
  float* dst = off + (size_t)n * 27 * HW + rem;
#pragma unroll
  for (int j = 0; j < 27; ++j) atomicAdd(&dst[(size_t)j * HW], acc[j]);
}

// ---------------------------------------------------------------------------
// Deformable bilinear sampling -> s[m_local][kk*C+c] (bf16).
// Thread per (pixel, tap); lanes span (hw,kk) so gathers cluster for L1/L2.
template <int C>
__global__ __launch_bounds__(256) void sample_kernel(
    const ushort_t* __restrict__ xbf, const float* __restrict__ off,
    ushort_t* __restrict__ s, int n0, int nspan) {
  int tg = blockIdx.x * 256 + threadIdx.x;   // nspan*HW*9 (exact)
  int kk = tg % 9;
  int ml = tg / 9;
  int nl = ml / HW, hw = ml % HW;
  int n = n0 + nl;
  int h = hw / W_, w = hw % W_;
  const float* offp = off + (size_t)n * 27 * HW + hw;
  float dy = offp[(size_t)(2 * kk) * HW];
  float dx = offp[(size_t)(2 * kk + 1) * HW];
  float mo = offp[(size_t)(18 + kk) * HW];
  float mm = 1.f / (1.f + __expf(-mo));
  float py = dy + (float)(kk / 3 - 1 + h);
  float px = dx + (float)(kk % 3 - 1 + w);
  float fy = floorf(py), fx = floorf(px);
  int y0 = (int)fy, x0 = (int)fx;
  float ly = py - fy, lx = px - fx;
  int y1 = y0 + 1, x1 = x0 + 1;
  bool vy0 = (y0 >= 0) & (y0 < H_), vy1 = (y1 >= 0) & (y1 < H_);
  bool vx0 = (x0 >= 0) & (x0 < W_), vx1 = (x1 >= 0) & (x1 < W_);
  int y0c = min(max(y0, 0), H_ - 1), y1c = min(max(y1, 0), H_ - 1);
  int x0c = min(max(x0, 0), W_ - 1), x1c = min(max(x1, 0), W_ - 1);
  float w00 = (vy0 & vx0) ? (1.f - ly) * (1.f - lx) * mm : 0.f;
  float w01 = (vy0 & vx1) ? (1.f - ly) * lx * mm : 0.f;
  float w10 = (vy1 & vx0) ? ly * (1.f - lx) * mm : 0.f;
  float w11 = (vy1 & vx1) ? ly * lx * mm : 0.f;
  int i00 = y0c * W_ + x0c, i01 = y0c * W_ + x1c;
  int i10 = y1c * W_ + x0c, i11 = y1c * W_ + x1c;
  const ushort_t* xbn = xbf + (size_t)n * C * HW;
  ushort_t* sp = s + ((size_t)ml * 9 + kk) * C;
  for (int c = 0; c < C; c += 8) {
    u16x8 r;
#pragma unroll
    for (int e = 0; e < 8; ++e) {
      const ushort_t* xp = xbn + (size_t)(c + e) * HW;
      float v = w00 * bf2f(xp[i00]) + w01 * bf2f(xp[i01])
              + w10 * bf2f(xp[i10]) + w11 * bf2f(xp[i11]);
      r[e] = f2bf(v);
    }
    *reinterpret_cast<u16x8*>(sp + c) = r;
  }
}

// ---------------------------------------------------------------------------
__device__ __forceinline__ void gll16(const ushort_t* g, ushort_t* l) {
  __builtin_amdgcn_global_load_lds((const __attribute__((address_space(1))) void*)g,
                                   (__attribute__((address_space(3))) void*)l, 16, 0, 0);
}

// row-dependent chunk swizzle: 8 consecutive rows hit distinct (row&1, slot)
// combos -> 2-way LDS aliasing (free) instead of 4-way.
__device__ __forceinline__ int swz(int row) {
  return (row & 3) ^ ((row >> 2) & 3);
}

// bf16 MFMA GEMM: A = s [M][K] row-major, B = wB [O=128][K] (B^T), Y [M][128] fp32.
// Tile 64m x 128o, 4 waves (2x2), wave 32m x 64o = 2x4 16x16 frags.
template <int K>
__global__ __launch_bounds__(256) void gemm_kernel(
    const ushort_t* __restrict__ A, const ushort_t* __restrict__ B,
    float* __restrict__ Y, int mbase) {
  __shared__ __align__(16) ushort_t As[64 * 32];
  __shared__ __align__(16) ushort_t Bs[128 * 32];
  int tid = threadIdx.x;
  int m0 = blockIdx.x * 64;
  int lane = tid & 63, wid = tid >> 6;
  int wr = wid >> 1, wc = wid & 1;
  f32x4 acc[2][4];
#pragma unroll
  for (int mi = 0; mi < 2; ++mi)
#pragma unroll
    for (int oi = 0; oi < 4; ++oi) acc[mi][oi] = (f32x4){0.f, 0.f, 0.f, 0.f};

  int srow = tid >> 2;        // staging row 0..63
  int chl = tid & 3;          // LDS chunk slot
  int q = lane >> 4;

  for (int kt = 0; kt < K; kt += 32) {
    {  // A: 64 rows x 64B, 1 round; source-side XOR swizzle
      int chg = chl ^ swz(srow);
      gll16(A + (size_t)(m0 + srow) * K + kt + chg * 8, As + tid * 8);
    }
#pragma unroll
    for (int rr = 0; rr < 2; ++rr) {  // B: 128 rows, 2 rounds
      int row = srow + 64 * rr;
      int chg = chl ^ swz(row);
      gll16(B + (size_t)row * K + kt + chg * 8, Bs + rr * 2048 + tid * 8);
    }
    __syncthreads();
    bf16x8 af[2], bfr[4];
#pragma unroll
    for (int mi = 0; mi < 2; ++mi) {
      int r = wr * 32 + mi * 16 + (lane & 15);
      af[mi] = *reinterpret_cast<const bf16x8*>(&As[r * 32 + ((q ^ swz(r)) << 3)]);
    }
#pragma unroll
    for (int oi = 0; oi < 4; ++oi) {
      int r = wc * 64 + oi * 16 + (lane & 15);
      bfr[oi] = *reinterpret_cast<const bf16x8*>(&Bs[r * 32 + ((q ^ swz(r)) << 3)]);
    }
#pragma unroll
    for (int mi = 0; mi < 2; ++mi)
#pragma unroll
      for (int oi = 0; oi < 4; ++oi)
        acc[mi][oi] = __builtin_amdgcn_mfma_f32_16x16x32_bf16(af[mi], bfr[oi], acc[mi][oi], 0, 0, 0);
    __syncthreads();
  }
#pragma unroll
  for (int mi = 0; mi < 2; ++mi)
#pragma unroll
    for (int oi = 0; oi < 4; ++oi) {
      int o = wc * 64 + oi * 16 + (lane & 15);
      int mb = m0 + wr * 32 + mi * 16 + ((lane >> 4) << 2);
#pragma unroll
      for (int j = 0; j < 4; ++j)
        Y[(size_t)(mbase + mb + j) * O_ + o] = acc[mi][oi][j];
    }
}

// ---------------------------------------------------------------------------
// BN stats over Y[m][o]: per-channel sum / sumsq via coalesced loads + atomics
__global__ __launch_bounds__(256) void bn_stats_kernel(const float* __restrict__ Y,
                                                       float* __restrict__ stats) {
  int o = threadIdx.x & 127;
  int seg = blockIdx.x * 2 + (threadIdx.x >> 7);   // 512 segs x 72 rows
  const float* p = Y + (size_t)seg * 72 * O_ + o;
  float s = 0.f, s2 = 0.f;
#pragma unroll 4
  for (int mm = 0; mm < 72; ++mm) {
    float v = p[(size_t)mm * O_];
    s += v; s2 += v * v;
  }
  atomicAdd(&stats[o], s);
  atomicAdd(&stats[128 + o], s2);
}

// BN apply + ReLU, transposing [m][o] -> [n][o][hw]; optional fp32 / bf16 outs
__global__ __launch_bounds__(256) void bn_apply_t_kernel(
    const float* __restrict__ Y, const float* __restrict__ stats,
    const float* __restrict__ gamma, const float* __restrict__ beta,
    float* __restrict__ outf, ushort_t* __restrict__ outb) {
  __shared__ float L[64][129];
  __shared__ float Lsc[128], Lsh[128];
  int tid = threadIdx.x;
  int m0 = blockIdx.x * 64;
  if (tid < 128) {
    float mu = stats[tid] * (1.f / (float)NHW);
    float var = stats[128 + tid] * (1.f / (float)NHW) - mu * mu;
    float sc = rsqrtf(var + 1e-5f) * gamma[tid];
    Lsc[tid] = sc;
    Lsh[tid] = beta[tid] - mu * sc;
  }
#pragma unroll
  for (int it = 0; it < 8; ++it) {
    int idx = it * 256 + tid;
    int ml = idx >> 5, oq = idx & 31;
    float4 v = *reinterpret_cast<const float4*>(&Y[(size_t)(m0 + ml) * O_ + oq * 4]);
    L[ml][oq * 4 + 0] = v.x; L[ml][oq * 4 + 1] = v.y;
    L[ml][oq * 4 + 2] = v.z; L[ml][oq * 4 + 3] = v.w;
  }
  __syncthreads();
  int n = m0 / HW, hw0 = m0 % HW;
#pragma unroll
  for (int it = 0; it < 32; ++it) {
    int idx = it * 256 + tid;
    int ol = idx >> 6, ml = idx & 63;
    float r = fmaxf(fmaf(L[ml][ol], Lsc[ol], Lsh[ol]), 0.f);
    size_t oi = ((size_t)n * O_ + ol) * HW + hw0 + ml;
    if (outf) outf[oi] = r;
    if (outb) outb[oi] = f2bf(r);
  }
}

// ---------------------------------------------------------------------------
extern "C" void kernel_launch(void* const* d_in, const int* in_sizes, int n_in,
                              void* d_out, int out_size, void* d_ws, size_t ws_size,
                              hipStream_t stream) {
  const float* x      = (const float*)d_in[0];
  const float* w1     = (const float*)d_in[1];
  const float* off_w1 = (const float*)d_in[2];
  const float* off_b1 = (const float*)d_in[3];
  const float* gamma1 = (const float*)d_in[4];
  const float* beta1  = (const float*)d_in[5];
  const float* w2     = (const float*)d_in[6];
  const float* off_w2 = (const float*)d_in[7];
  const float* off_b2 = (const float*)d_in[8];
  const float* gamma2 = (const float*)d_in[9];
  const float* beta2  = (const float*)d_in[10];
  float* out = (float*)d_out;

  char* p = (char*)d_ws;
  auto alloc = [&](size_t bytes) -> void* {
    void* r = (void*)p;
    p += (bytes + 255) & ~(size_t)255;
    return r;
  };
  float*    off   = (float*)alloc((size_t)N_ * 27 * HW * 4);        // 3.98 MB
  float*    Y     = (float*)alloc((size_t)NHW * O_ * 4);            // 18.9 MB
  float*    owT1  = (float*)alloc(16128 * 4);
  float*    owT2  = (float*)alloc(32256 * 4);
  float*    stats = (float*)alloc(512 * 4);
  ushort_t* wB1   = (ushort_t*)alloc(73728 * 2);
  ushort_t* wB2   = (ushort_t*)alloc(147456 * 2);
  ushort_t* xbf   = (ushort_t*)alloc((size_t)N_ * 64 * HW * 2);     // 4.7 MB
  ushort_t* hbf   = (ushort_t*)alloc((size_t)N_ * 128 * HW * 2);    // 9.4 MB
  size_t used = (size_t)(p - (char*)d_ws);
  size_t s_full = (size_t)NHW * 1152 * 2;                           // 84.9 MB
  int nspan = (ws_size >= used + s_full) ? 4 : 1;                   // chunk if tight
  ushort_t* sbuf = (ushort_t*)p;

  // prep
  f32_to_bf16_kernel<<<1152, 256, 0, stream>>>(x, xbf, 294912);
  transpose_w_kernel<<<288, 256, 0, stream>>>(w1, wB1, 64);
  transpose_w_kernel<<<576, 256, 0, stream>>>(w2, wB2, 128);
  transpose_ow_kernel<<<63, 256, 0, stream>>>(off_w1, owT1, 64);
  transpose_ow_kernel<<<126, 256, 0, stream>>>(off_w2, owT2, 128);
  hipMemsetAsync(stats, 0, 512 * 4, stream);

  // ---- layer 1 (C=64, K=576) ----
  bias_fill_kernel<<<3888, 256, 0, stream>>>(off, off_b1);
  offset_conv_kernel<<<576, 256, 0, stream>>>(xbf, owT1, off, 64);
  for (int n0 = 0; n0 < 4; n0 += nspan) {
    sample_kernel<64><<<nspan * 324, 256, 0, stream>>>(xbf, off, sbuf, n0, nspan);
    gemm_kernel<576><<<nspan * 144, 256, 0, stream>>>(sbuf, wB1, Y, n0 * HW);
  }
  bn_stats_kernel<<<256, 256, 0, stream>>>(Y, stats);
  bn_apply_t_kernel<<<576, 256, 0, stream>>>(Y, stats, gamma1, beta1, nullptr, hbf);

  // ---- layer 2 (C=128, K=1152) ----
  bias_fill_kernel<<<3888, 256, 0, stream>>>(off, off_b2);
  offset_conv_kernel<<<576, 256, 0, stream>>>(hbf, owT2, off, 128);
  for (int n0 = 0; n0 < 4; n0 += nspan) {
    sample_kernel<128><<<nspan * 324, 256, 0, stream>>>(hbf, off, sbuf, n0, nspan);
    gemm_kernel<1152><<<nspan * 144, 256, 0, stream>>>(sbuf, wB2, Y, n0 * HW);
  }
  bn_stats_kernel<<<256, 256, 0, stream>>>(Y, stats + 256);
  bn_apply_t_kernel<<<576, 256, 0, stream>>>(Y, stats + 256, gamma2, beta2, out, nullptr);
}

// Round 8
// 384.252 us; speedup vs baseline: 2.5044x; 2.1359x over previous
//
#include <hip/hip_runtime.h>
#include <math.h>

#define N_  4
#define H_  96
#define W_  96
#define HW  9216          // H*W
#define NHW 36864         // N*H*W
#define O_  128

typedef unsigned short ushort_t;
typedef __attribute__((ext_vector_type(8))) short bf16x8;
typedef __attribute__((ext_vector_type(4))) float f32x4;
typedef __attribute__((ext_vector_type(8))) unsigned short u16x8;

__device__ __forceinline__ float bf2f(ushort_t u) {
  return __uint_as_float(((unsigned int)u) << 16);
}
__device__ __forceinline__ ushort_t f2bf(float f) {
  unsigned int u = __float_as_uint(f);
  u += 0x7fffu + ((u >> 16) & 1u);           // RNE
  return (ushort_t)(u >> 16);
}

// ---------------------------------------------------------------------------
// NCHW fp32 -> NHWC bf16 tile transpose (32x32 tiles via LDS)
__global__ __launch_bounds__(256) void to_nhwc_kernel(const float* __restrict__ x,
                                                      ushort_t* __restrict__ xt, int C) {
  __shared__ ushort_t L[32][33];
  int ctiles = C >> 5;
  int b = blockIdx.x;
  int ct = b % ctiles;
  int hwt = (b / ctiles) % (HW / 32);
  int n = b / (ctiles * (HW / 32));
  int tx = threadIdx.x & 31, ty = threadIdx.x >> 5;
#pragma unroll
  for (int i = 0; i < 4; ++i) {
    int cl = ty + i * 8;
    L[cl][tx] = f2bf(x[((size_t)(n * C + ct * 32 + cl)) * HW + hwt * 32 + tx]);
  }
  __syncthreads();
#pragma unroll
  for (int i = 0; i < 4; ++i) {
    int hl = ty + i * 8;
    xt[((size_t)n * HW + hwt * 32 + hl) * C + ct * 32 + tx] = L[tx][hl];
  }
}

// wB[o][kk*C+c] = bf16(w[o][c][kk])   (B^T layout for MFMA)
__global__ void transpose_w_kernel(const float* __restrict__ w,
                                   ushort_t* __restrict__ wB, int C) {
  int K = C * 9;
  int i = blockIdx.x * 256 + threadIdx.x;
  if (i >= 128 * K) return;
  int o = i / K, r = i % K;
  int kk = r / C, c = r % C;
  wB[i] = f2bf(w[(o * C + c) * 9 + kk]);
}

// wOB[o][kk*C+c] = bf16(off_w[o][c][kk]) for o<27, zeros for o in [27,32)
__global__ void transpose_wo_kernel(const float* __restrict__ ow,
                                    ushort_t* __restrict__ wOB, int C) {
  int K = C * 9;
  int i = blockIdx.x * 256 + threadIdx.x;
  if (i >= 32 * K) return;
  int o = i / K, r = i % K;
  int kk = r / C, c = r % C;
  wOB[i] = (o < 27) ? f2bf(ow[(o * C + c) * 9 + kk]) : (ushort_t)0;
}

// ---------------------------------------------------------------------------
// im2col for the 3x3 offset conv: A[ml][kk*C+c] = xt[n][hw+shift(kk)][c] or 0
template <int C>
__global__ __launch_bounds__(256) void im2col_kernel(
    const ushort_t* __restrict__ xt, ushort_t* __restrict__ A, int n0) {
  constexpr int CH = C / 8;
  int g = blockIdx.x * 256 + threadIdx.x;      // nspan*HW*9*CH (exact)
  int cc = g % CH;
  int t = g / CH;
  int kk = t % 9;
  int ml = t / 9;
  int nl = ml / HW, hw = ml % HW;
  int h = hw / W_, w = hw % W_;
  int y = h + kk / 3 - 1, xx = w + kk % 3 - 1;
  u16x8 v;
#pragma unroll
  for (int e = 0; e < 8; ++e) v[e] = 0;
  if (y >= 0 && y < H_ && xx >= 0 && xx < W_)
    v = *reinterpret_cast<const u16x8*>(
        xt + ((size_t)(n0 + nl) * HW + y * W_ + xx) * C + cc * 8);
  *reinterpret_cast<u16x8*>(A + ((size_t)ml * 9 + kk) * C + cc * 8) = v;
}

// ---------------------------------------------------------------------------
__device__ __forceinline__ void gll16(const ushort_t* g, ushort_t* l) {
  __builtin_amdgcn_global_load_lds((const __attribute__((address_space(1))) void*)g,
                                   (__attribute__((address_space(3))) void*)l, 16, 0, 0);
}
__device__ __forceinline__ int swz(int row) {
  return (row & 3) ^ ((row >> 2) & 3);
}

// Offset-conv GEMM: A [M][K], B=wOB [32][K], out off_t[m][28] fp32 (+bias), o<27.
// Block: 64m x 32o, 4 waves each 16m x 32o.
template <int K>
__global__ __launch_bounds__(256) void gemm_off_kernel(
    const ushort_t* __restrict__ A, const ushort_t* __restrict__ B,
    const float* __restrict__ ob, float* __restrict__ offt, int mbase) {
  __shared__ __align__(16) ushort_t As[64 * 32];
  __shared__ __align__(16) ushort_t Bs[32 * 32];
  int tid = threadIdx.x;
  int m0 = blockIdx.x * 64;
  int lane = tid & 63, wid = tid >> 6;
  f32x4 acc[2];
  acc[0] = (f32x4){0.f, 0.f, 0.f, 0.f};
  acc[1] = (f32x4){0.f, 0.f, 0.f, 0.f};
  int srow = tid >> 2, chl = tid & 3, q = lane >> 4;
  for (int kt = 0; kt < K; kt += 32) {
    gll16(A + (size_t)(m0 + srow) * K + kt + (chl ^ swz(srow)) * 8, As + tid * 8);
    if (tid < 128) {
      int row = tid >> 2;
      gll16(B + (size_t)row * K + kt + (chl ^ swz(row)) * 8, Bs + tid * 8);
    }
    __syncthreads();
    int r = wid * 16 + (lane & 15);
    bf16x8 af = *reinterpret_cast<const bf16x8*>(&As[r * 32 + ((q ^ swz(r)) << 3)]);
#pragma unroll
    for (int oi = 0; oi < 2; ++oi) {
      int rb = oi * 16 + (lane & 15);
      bf16x8 bfr = *reinterpret_cast<const bf16x8*>(&Bs[rb * 32 + ((q ^ swz(rb)) << 3)]);
      acc[oi] = __builtin_amdgcn_mfma_f32_16x16x32_bf16(af, bfr, acc[oi], 0, 0, 0);
    }
    __syncthreads();
  }
#pragma unroll
  for (int oi = 0; oi < 2; ++oi) {
    int o = oi * 16 + (lane & 15);
    if (o < 27) {
      float b = ob[o];
      int mb = m0 + wid * 16 + ((lane >> 4) << 2);
#pragma unroll
      for (int j = 0; j < 4; ++j)
        offt[(size_t)(mbase + mb + j) * 28 + o] = acc[oi][j] + b;
    }
  }
}

// ---------------------------------------------------------------------------
// Deformable bilinear sampling (NHWC input) -> s[ml][kk*C+c] (bf16).
template <int C>
__global__ __launch_bounds__(256) void sample_nhwc_kernel(
    const ushort_t* __restrict__ xt, const float* __restrict__ offt,
    ushort_t* __restrict__ s, int n0) {
  int tg = blockIdx.x * 256 + threadIdx.x;   // nspan*HW*9 (exact)
  int kk = tg % 9;
  int ml = tg / 9;
  int nl = ml / HW, hw = ml % HW;
  int h = hw / W_, w = hw % W_;
  const float* op = offt + ((size_t)n0 * HW + ml) * 28;
  float dy = op[2 * kk];
  float dx = op[2 * kk + 1];
  float mo = op[18 + kk];
  float mm = 1.f / (1.f + __expf(-mo));
  float py = dy + (float)(kk / 3 - 1 + h);
  float px = dx + (float)(kk % 3 - 1 + w);
  float fy = floorf(py), fx = floorf(px);
  int y0 = (int)fy, x0 = (int)fx;
  float ly = py - fy, lx = px - fx;
  int y1 = y0 + 1, x1 = x0 + 1;
  bool vy0 = (y0 >= 0) & (y0 < H_), vy1 = (y1 >= 0) & (y1 < H_);
  bool vx0 = (x0 >= 0) & (x0 < W_), vx1 = (x1 >= 0) & (x1 < W_);
  int y0c = min(max(y0, 0), H_ - 1), y1c = min(max(y1, 0), H_ - 1);
  int x0c = min(max(x0, 0), W_ - 1), x1c = min(max(x1, 0), W_ - 1);
  float w00 = (vy0 & vx0) ? (1.f - ly) * (1.f - lx) * mm : 0.f;
  float w01 = (vy0 & vx1) ? (1.f - ly) * lx * mm : 0.f;
  float w10 = (vy1 & vx0) ? ly * (1.f - lx) * mm : 0.f;
  float w11 = (vy1 & vx1) ? ly * lx * mm : 0.f;
  const ushort_t* xb = xt + (size_t)(n0 + nl) * HW * C;
  const ushort_t* p00 = xb + (size_t)(y0c * W_ + x0c) * C;
  const ushort_t* p01 = xb + (size_t)(y0c * W_ + x1c) * C;
  const ushort_t* p10 = xb + (size_t)(y1c * W_ + x0c) * C;
  const ushort_t* p11 = xb + (size_t)(y1c * W_ + x1c) * C;
  ushort_t* sp = s + ((size_t)ml * 9 + kk) * C;
  for (int c = 0; c < C; c += 8) {
    u16x8 a = *reinterpret_cast<const u16x8*>(p00 + c);
    u16x8 b = *reinterpret_cast<const u16x8*>(p01 + c);
    u16x8 cc = *reinterpret_cast<const u16x8*>(p10 + c);
    u16x8 d = *reinterpret_cast<const u16x8*>(p11 + c);
    u16x8 r;
#pragma unroll
    for (int e = 0; e < 8; ++e) {
      float v = w00 * bf2f(a[e]) + w01 * bf2f(b[e])
              + w10 * bf2f(cc[e]) + w11 * bf2f(d[e]);
      r[e] = f2bf(v);
    }
    *reinterpret_cast<u16x8*>(sp + c) = r;
  }
}

// ---------------------------------------------------------------------------
// Main MFMA GEMM: A=s [M][K], B=wB [128][K], Y [M][128] fp32.
// Tile 64m x 128o, 4 waves (2x2), wave 32m x 64o.
template <int K>
__global__ __launch_bounds__(256) void gemm_kernel(
    const ushort_t* __restrict__ A, const ushort_t* __restrict__ B,
    float* __restrict__ Y, int mbase) {
  __shared__ __align__(16) ushort_t As[64 * 32];
  __shared__ __align__(16) ushort_t Bs[128 * 32];
  int tid = threadIdx.x;
  int m0 = blockIdx.x * 64;
  int lane = tid & 63, wid = tid >> 6;
  int wr = wid >> 1, wc = wid & 1;
  f32x4 acc[2][4];
#pragma unroll
  for (int mi = 0; mi < 2; ++mi)
#pragma unroll
    for (int oi = 0; oi < 4; ++oi) acc[mi][oi] = (f32x4){0.f, 0.f, 0.f, 0.f};
  int srow = tid >> 2, chl = tid & 3, q = lane >> 4;
  for (int kt = 0; kt < K; kt += 32) {
    gll16(A + (size_t)(m0 + srow) * K + kt + (chl ^ swz(srow)) * 8, As + tid * 8);
#pragma unroll
    for (int rr = 0; rr < 2; ++rr) {
      int row = srow + 64 * rr;
      gll16(B + (size_t)row * K + kt + (chl ^ swz(row)) * 8, Bs + rr * 2048 + tid * 8);
    }
    __syncthreads();
    bf16x8 af[2], bfr[4];
#pragma unroll
    for (int mi = 0; mi < 2; ++mi) {
      int r = wr * 32 + mi * 16 + (lane & 15);
      af[mi] = *reinterpret_cast<const bf16x8*>(&As[r * 32 + ((q ^ swz(r)) << 3)]);
    }
#pragma unroll
    for (int oi = 0; oi < 4; ++oi) {
      int r = wc * 64 + oi * 16 + (lane & 15);
      bfr[oi] = *reinterpret_cast<const bf16x8*>(&Bs[r * 32 + ((q ^ swz(r)) << 3)]);
    }
#pragma unroll
    for (int mi = 0; mi < 2; ++mi)
#pragma unroll
      for (int oi = 0; oi < 4; ++oi)
        acc[mi][oi] = __builtin_amdgcn_mfma_f32_16x16x32_bf16(af[mi], bfr[oi], acc[mi][oi], 0, 0, 0);
    __syncthreads();
  }
#pragma unroll
  for (int mi = 0; mi < 2; ++mi)
#pragma unroll
    for (int oi = 0; oi < 4; ++oi) {
      int o = wc * 64 + oi * 16 + (lane & 15);
      int mb = m0 + wr * 32 + mi * 16 + ((lane >> 4) << 2);
#pragma unroll
      for (int j = 0; j < 4; ++j)
        Y[(size_t)(mbase + mb + j) * O_ + o] = acc[mi][oi][j];
    }
}

// ---------------------------------------------------------------------------
__global__ __launch_bounds__(256) void bn_stats_kernel(const float* __restrict__ Y,
                                                       float* __restrict__ stats) {
  int o = threadIdx.x & 127;
  int seg = blockIdx.x * 2 + (threadIdx.x >> 7);   // 512 segs x 72 rows
  const float* p = Y + (size_t)seg * 72 * O_ + o;
  float s = 0.f, s2 = 0.f;
#pragma unroll 4
  for (int mm = 0; mm < 72; ++mm) {
    float v = p[(size_t)mm * O_];
    s += v; s2 += v * v;
  }
  atomicAdd(&stats[o], s);
  atomicAdd(&stats[128 + o], s2);
}

// BN+ReLU elementwise, Y[m][o] fp32 -> ht[m][o] bf16 (NHWC, no transpose)
__global__ __launch_bounds__(256) void bn_apply_nhwc_kernel(
    const float* __restrict__ Y, const float* __restrict__ stats,
    const float* __restrict__ gamma, const float* __restrict__ beta,
    ushort_t* __restrict__ ht) {
  int g = blockIdx.x * 256 + threadIdx.x;    // NHW*16
  int o0 = (g & 15) * 8;
  const float4* yp = reinterpret_cast<const float4*>(Y) + (size_t)g * 2;
  float4 a = yp[0], b = yp[1];
  float va[8] = {a.x, a.y, a.z, a.w, b.x, b.y, b.z, b.w};
  u16x8 r;
#pragma unroll
  for (int e = 0; e < 8; ++e) {
    int o = o0 + e;
    float mu = stats[o] * (1.f / (float)NHW);
    float var = stats[128 + o] * (1.f / (float)NHW) - mu * mu;
    float sc = rsqrtf(var + 1e-5f) * gamma[o];
    float sh = beta[o] - mu * sc;
    r[e] = f2bf(fmaxf(fmaf(va[e], sc, sh), 0.f));
  }
  *reinterpret_cast<u16x8*>(ht + (size_t)g * 8) = r;
}

// BN apply + ReLU, transposing [m][o] -> [n][o][hw] fp32 (final output)
__global__ __launch_bounds__(256) void bn_apply_t_kernel(
    const float* __restrict__ Y, const float* __restrict__ stats,
    const float* __restrict__ gamma, const float* __restrict__ beta,
    float* __restrict__ outf) {
  __shared__ float L[64][129];
  __shared__ float Lsc[128], Lsh[128];
  int tid = threadIdx.x;
  int m0 = blockIdx.x * 64;
  if (tid < 128) {
    float mu = stats[tid] * (1.f / (float)NHW);
    float var = stats[128 + tid] * (1.f / (float)NHW) - mu * mu;
    float sc = rsqrtf(var + 1e-5f) * gamma[tid];
    Lsc[tid] = sc;
    Lsh[tid] = beta[tid] - mu * sc;
  }
#pragma unroll
  for (int it = 0; it < 8; ++it) {
    int idx = it * 256 + tid;
    int ml = idx >> 5, oq = idx & 31;
    float4 v = *reinterpret_cast<const float4*>(&Y[(size_t)(m0 + ml) * O_ + oq * 4]);
    L[ml][oq * 4 + 0] = v.x; L[ml][oq * 4 + 1] = v.y;
    L[ml][oq * 4 + 2] = v.z; L[ml][oq * 4 + 3] = v.w;
  }
  __syncthreads();
  int n = m0 / HW, hw0 = m0 % HW;
#pragma unroll
  for (int it = 0; it < 32; ++it) {
    int idx = it * 256 + tid;
    int ol = idx >> 6, ml = idx & 63;
    float r = fmaxf(fmaf(L[ml][ol], Lsc[ol], Lsh[ol]), 0.f);
    outf[((size_t)n * O_ + ol) * HW + hw0 + ml] = r;
  }
}

// ---------------------------------------------------------------------------
extern "C" void kernel_launch(void* const* d_in, const int* in_sizes, int n_in,
                              void* d_out, int out_size, void* d_ws, size_t ws_size,
                              hipStream_t stream) {
  const float* x      = (const float*)d_in[0];
  const float* w1     = (const float*)d_in[1];
  const float* off_w1 = (const float*)d_in[2];
  const float* off_b1 = (const float*)d_in[3];
  const float* gamma1 = (const float*)d_in[4];
  const float* beta1  = (const float*)d_in[5];
  const float* w2     = (const float*)d_in[6];
  const float* off_w2 = (const float*)d_in[7];
  const float* off_b2 = (const float*)d_in[8];
  const float* gamma2 = (const float*)d_in[9];
  const float* beta2  = (const float*)d_in[10];
  float* out = (float*)d_out;

  char* p = (char*)d_ws;
  auto alloc = [&](size_t bytes) -> void* {
    void* r = (void*)p;
    p += (bytes + 255) & ~(size_t)255;
    return r;
  };
  float*    offt  = (float*)alloc((size_t)NHW * 28 * 4);            // 4.13 MB
  float*    Y     = (float*)alloc((size_t)NHW * O_ * 4);            // 18.9 MB
  float*    stats = (float*)alloc(512 * 4);
  ushort_t* wB1   = (ushort_t*)alloc(73728 * 2);
  ushort_t* wB2   = (ushort_t*)alloc(147456 * 2);
  ushort_t* wOB1  = (ushort_t*)alloc(32 * 576 * 2);
  ushort_t* wOB2  = (ushort_t*)alloc(32 * 1152 * 2);
  ushort_t* xt    = (ushort_t*)alloc((size_t)NHW * 64 * 2);         // 4.7 MB
  ushort_t* ht    = (ushort_t*)alloc((size_t)NHW * 128 * 2);        // 9.4 MB
  size_t used = (size_t)(p - (char*)d_ws);
  size_t s_full = (size_t)NHW * 1152 * 2;                           // 84.9 MB
  int nspan = (ws_size >= used + s_full) ? 4 : 1;                   // chunk if tight
  ushort_t* sbuf = (ushort_t*)p;

  // prep
  to_nhwc_kernel<<<2304, 256, 0, stream>>>(x, xt, 64);
  transpose_w_kernel<<<288, 256, 0, stream>>>(w1, wB1, 64);
  transpose_w_kernel<<<576, 256, 0, stream>>>(w2, wB2, 128);
  transpose_wo_kernel<<<72, 256, 0, stream>>>(off_w1, wOB1, 64);
  transpose_wo_kernel<<<144, 256, 0, stream>>>(off_w2, wOB2, 128);
  hipMemsetAsync(stats, 0, 512 * 4, stream);

  // ---- layer 1 (C=64, K=576) ----
  for (int n0 = 0; n0 < 4; n0 += nspan) {
    im2col_kernel<64><<<nspan * 2592, 256, 0, stream>>>(xt, sbuf, n0);
    gemm_off_kernel<576><<<nspan * 144, 256, 0, stream>>>(sbuf, wOB1, off_b1, offt, n0 * HW);
    sample_nhwc_kernel<64><<<nspan * 324, 256, 0, stream>>>(xt, offt, sbuf, n0);
    gemm_kernel<576><<<nspan * 144, 256, 0, stream>>>(sbuf, wB1, Y, n0 * HW);
  }
  bn_stats_kernel<<<256, 256, 0, stream>>>(Y, stats);
  bn_apply_nhwc_kernel<<<2304, 256, 0, stream>>>(Y, stats, gamma1, beta1, ht);

  // ---- layer 2 (C=128, K=1152) ----
  for (int n0 = 0; n0 < 4; n0 += nspan) {
    im2col_kernel<128><<<nspan * 5184, 256, 0, stream>>>(ht, sbuf, n0);
    gemm_off_kernel<1152><<<nspan * 144, 256, 0, stream>>>(sbuf, wOB2, off_b2, offt, n0 * HW);
    sample_nhwc_kernel<128><<<nspan * 324, 256, 0, stream>>>(ht, offt, sbuf, n0);
    gemm_kernel<1152><<<nspan * 144, 256, 0, stream>>>(sbuf, wB2, Y, n0 * HW);
  }
  bn_stats_kernel<<<256, 256, 0, stream>>>(Y, stats + 256);
  bn_apply_t_kernel<<<576, 256, 0, stream>>>(Y, stats + 256, gamma2, beta2, out);
}

// Round 10
// 263.580 us; speedup vs baseline: 3.6510x; 1.4578x over previous
//
#include <hip/hip_runtime.h>
#include <math.h>

#define N_  4
#define H_  96
#define W_  96
#define HW  9216          // H*W
#define NHW 36864         // N*H*W
#define O_  128
#define PW  98            // padded width/height
#define PHW 9604          // PW*PW

typedef unsigned short ushort_t;
typedef __attribute__((ext_vector_type(8))) short bf16x8;
typedef __attribute__((ext_vector_type(4))) float f32x4;
typedef __attribute__((ext_vector_type(8))) unsigned short u16x8;

__device__ __forceinline__ float bf2f(ushort_t u) {
  return __uint_as_float(((unsigned int)u) << 16);
}
__device__ __forceinline__ ushort_t f2bf(float f) {
  unsigned int u = __float_as_uint(f);
  u += 0x7fffu + ((u >> 16) & 1u);           // RNE
  return (ushort_t)(u >> 16);
}

// ---------------------------------------------------------------------------
// NCHW fp32 -> padded NHWC bf16 ([n][98][98][C], interior only; borders memset)
__global__ __launch_bounds__(256) void to_nhwc_pad_kernel(const float* __restrict__ x,
                                                          ushort_t* __restrict__ xp, int C) {
  __shared__ ushort_t L[32][33];
  int ctiles = C >> 5;
  int b = blockIdx.x;
  int ct = b % ctiles;
  int hwt = (b / ctiles) % (HW / 32);
  int n = b / (ctiles * (HW / 32));
  int tx = threadIdx.x & 31, ty = threadIdx.x >> 5;
#pragma unroll
  for (int i = 0; i < 4; ++i) {
    int cl = ty + i * 8;
    L[cl][tx] = f2bf(x[((size_t)(n * C + ct * 32 + cl)) * HW + hwt * 32 + tx]);
  }
  __syncthreads();
#pragma unroll
  for (int i = 0; i < 4; ++i) {
    int hl = ty + i * 8;
    int hw = hwt * 32 + hl;
    int y = hw / W_, xx = hw % W_;
    xp[((size_t)n * PHW + (y + 1) * PW + (xx + 1)) * C + ct * 32 + tx] = L[tx][hl];
  }
}

// wB[o][kk*C+c] = bf16(w[o][c][kk])   (B^T layout for MFMA)
__global__ void transpose_w_kernel(const float* __restrict__ w,
                                   ushort_t* __restrict__ wB, int C) {
  int K = C * 9;
  int i = blockIdx.x * 256 + threadIdx.x;
  if (i >= 128 * K) return;
  int o = i / K, r = i % K;
  int kk = r / C, c = r % C;
  wB[i] = f2bf(w[(o * C + c) * 9 + kk]);
}

// wOB[o][kk*C+c] = bf16(off_w[o][c][kk]) for o<27, zeros for o in [27,32)
__global__ void transpose_wo_kernel(const float* __restrict__ ow,
                                    ushort_t* __restrict__ wOB, int C) {
  int K = C * 9;
  int i = blockIdx.x * 256 + threadIdx.x;
  if (i >= 32 * K) return;
  int o = i / K, r = i % K;
  int kk = r / C, c = r % C;
  wOB[i] = (o < 27) ? f2bf(ow[(o * C + c) * 9 + kk]) : (ushort_t)0;
}

// ---------------------------------------------------------------------------
__device__ __forceinline__ void gll16(const ushort_t* g, ushort_t* l) {
  __builtin_amdgcn_global_load_lds((const __attribute__((address_space(1))) void*)g,
                                   (__attribute__((address_space(3))) void*)l, 16, 0, 0);
}
__device__ __forceinline__ int swz(int row) {
  return (row & 3) ^ ((row >> 2) & 3);
}

// Offset-conv GEMM with implicit im2col from padded NHWC.
// A[m][kk*C+c] = xp[n][y+ky][x+kx][c] (zero ring = conv padding).
// Block: 64m x 32o, 4 waves each 16m x 32o.
template <int C>
__global__ __launch_bounds__(256) void gemm_off_kernel(
    const ushort_t* __restrict__ xp, const ushort_t* __restrict__ B,
    const float* __restrict__ ob, float* __restrict__ offt, int n0) {
  constexpr int K = C * 9;
  __shared__ __align__(16) ushort_t As[64 * 32];
  __shared__ __align__(16) ushort_t Bs[32 * 32];
  int tid = threadIdx.x;
  int m0 = blockIdx.x * 64;                  // local m within chunk
  int lane = tid & 63, wid = tid >> 6;
  f32x4 acc[2];
  acc[0] = (f32x4){0.f, 0.f, 0.f, 0.f};
  acc[1] = (f32x4){0.f, 0.f, 0.f, 0.f};
  int srow = tid >> 2, chl = tid & 3, q = lane >> 4;
  // staging row -> pixel (fixed across K loop)
  int mg = m0 + srow;
  int nl = mg / HW, hw = mg % HW;
  int y = hw / W_, x = hw % W_;
  const ushort_t* xn = xp + (size_t)(n0 + nl) * PHW * C;
  int pbase = ((y + 1) * PW + (x + 1)) * C;
  int chg = chl ^ swz(srow);
  for (int kt = 0; kt < K; kt += 32) {
    int kk = kt / C, c0 = kt % C;
    int shift = ((kk / 3 - 1) * PW + (kk % 3 - 1)) * C;
    gll16(xn + pbase + shift + c0 + chg * 8, As + tid * 8);
    if (tid < 128) {
      int row = tid >> 2;
      gll16(B + (size_t)row * K + kt + ((tid & 3) ^ swz(row)) * 8, Bs + tid * 8);
    }
    __syncthreads();
    int r = wid * 16 + (lane & 15);
    bf16x8 af = *reinterpret_cast<const bf16x8*>(&As[r * 32 + ((q ^ swz(r)) << 3)]);
#pragma unroll
    for (int oi = 0; oi < 2; ++oi) {
      int rb = oi * 16 + (lane & 15);
      bf16x8 bfr = *reinterpret_cast<const bf16x8*>(&Bs[rb * 32 + ((q ^ swz(rb)) << 3)]);
      acc[oi] = __builtin_amdgcn_mfma_f32_16x16x32_bf16(af, bfr, acc[oi], 0, 0, 0);
    }
    __syncthreads();
  }
#pragma unroll
  for (int oi = 0; oi < 2; ++oi) {
    int o = oi * 16 + (lane & 15);
    if (o < 27) {
      float b = ob[o];
      int mb = n0 * HW + m0 + wid * 16 + ((lane >> 4) << 2);
#pragma unroll
      for (int j = 0; j < 4; ++j)
        offt[(size_t)(mb + j) * 28 + o] = acc[oi][j] + b;
    }
  }
}

// ---------------------------------------------------------------------------
// Deformable bilinear sampling (padded NHWC) -> s[ml][kk*C+c] (bf16).
// cc-FASTEST mapping: consecutive lanes = consecutive c-chunks of one
// (pixel,tap) row -> contiguous 1KB/wave stores, contiguous corner reads.
template <int C>
__global__ __launch_bounds__(256) void sample_nhwc_kernel(
    const ushort_t* __restrict__ xp, const float* __restrict__ offt,
    ushort_t* __restrict__ s, int n0) {
  constexpr int CH = C / 8;
  int g = blockIdx.x * 256 + threadIdx.x;   // nspan*HW*9*CH (exact)
  int cc = g % CH;
  int t = g / CH;
  int kk = t % 9;
  int ml = t / 9;
  int nl = ml / HW, hw = ml % HW;
  int h = hw / W_, w = hw % W_;
  const float* op = offt + ((size_t)n0 * HW + ml) * 28;
  float dy = op[2 * kk];
  float dx = op[2 * kk + 1];
  float mo = op[18 + kk];
  float mm = 1.f / (1.f + __expf(-mo));
  float py = dy + (float)(kk / 3 - 1 + h);
  float px = dx + (float)(kk % 3 - 1 + w);
  float fy = floorf(py), fx = floorf(px);
  int y0 = (int)fy, x0 = (int)fx;
  float ly = py - fy, lx = px - fx;
  int y1 = y0 + 1, x1 = x0 + 1;
  bool vy0 = (y0 >= 0) & (y0 < H_), vy1 = (y1 >= 0) & (y1 < H_);
  bool vx0 = (x0 >= 0) & (x0 < W_), vx1 = (x1 >= 0) & (x1 < W_);
  int y0c = min(max(y0, 0), H_ - 1), y1c = min(max(y1, 0), H_ - 1);
  int x0c = min(max(x0, 0), W_ - 1), x1c = min(max(x1, 0), W_ - 1);
  float w00 = (vy0 & vx0) ? (1.f - ly) * (1.f - lx) * mm : 0.f;
  float w01 = (vy0 & vx1) ? (1.f - ly) * lx * mm : 0.f;
  float w10 = (vy1 & vx0) ? ly * (1.f - lx) * mm : 0.f;
  float w11 = (vy1 & vx1) ? ly * lx * mm : 0.f;
  const ushort_t* xb = xp + (size_t)(n0 + nl) * PHW * C + cc * 8;
  const ushort_t* p00 = xb + (size_t)((y0c + 1) * PW + x0c + 1) * C;
  const ushort_t* p01 = xb + (size_t)((y0c + 1) * PW + x1c + 1) * C;
  const ushort_t* p10 = xb + (size_t)((y1c + 1) * PW + x0c + 1) * C;
  const ushort_t* p11 = xb + (size_t)((y1c + 1) * PW + x1c + 1) * C;
  u16x8 a = *reinterpret_cast<const u16x8*>(p00);
  u16x8 b = *reinterpret_cast<const u16x8*>(p01);
  u16x8 c2 = *reinterpret_cast<const u16x8*>(p10);
  u16x8 d = *reinterpret_cast<const u16x8*>(p11);
  u16x8 r;
#pragma unroll
  for (int e = 0; e < 8; ++e) {
    float v = w00 * bf2f(a[e]) + w01 * bf2f(b[e])
            + w10 * bf2f(c2[e]) + w11 * bf2f(d[e]);
    r[e] = f2bf(v);
  }
  *reinterpret_cast<u16x8*>(s + ((size_t)ml * 9 + kk) * C + cc * 8) = r;
}

// ---------------------------------------------------------------------------
// Main MFMA GEMM: A=s [M][K], B=wB [128][K], Y [M][128] fp32.
// Tile 64m x 128o, 4 waves (2x2), wave 32m x 64o.
template <int K>
__global__ __launch_bounds__(256) void gemm_kernel(
    const ushort_t* __restrict__ A, const ushort_t* __restrict__ B,
    float* __restrict__ Y, int mbase) {
  __shared__ __align__(16) ushort_t As[64 * 32];
  __shared__ __align__(16) ushort_t Bs[128 * 32];
  int tid = threadIdx.x;
  int m0 = blockIdx.x * 64;
  int lane = tid & 63, wid = tid >> 6;
  int wr = wid >> 1, wc = wid & 1;
  f32x4 acc[2][4];
#pragma unroll
  for (int mi = 0; mi < 2; ++mi)
#pragma unroll
    for (int oi = 0; oi < 4; ++oi) acc[mi][oi] = (f32x4){0.f, 0.f, 0.f, 0.f};
  int srow = tid >> 2, chl = tid & 3, q = lane >> 4;
  for (int kt = 0; kt < K; kt += 32) {
    gll16(A + (size_t)(m0 + srow) * K + kt + (chl ^ swz(srow)) * 8, As + tid * 8);
#pragma unroll
    for (int rr = 0; rr < 2; ++rr) {
      int row = srow + 64 * rr;
      gll16(B + (size_t)row * K + kt + (chl ^ swz(row)) * 8, Bs + rr * 2048 + tid * 8);
    }
    __syncthreads();
    bf16x8 af[2], bfr[4];
#pragma unroll
    for (int mi = 0; mi < 2; ++mi) {
      int r = wr * 32 + mi * 16 + (lane & 15);
      af[mi] = *reinterpret_cast<const bf16x8*>(&As[r * 32 + ((q ^ swz(r)) << 3)]);
    }
#pragma unroll
    for (int oi = 0; oi < 4; ++oi) {
      int r = wc * 64 + oi * 16 + (lane & 15);
      bfr[oi] = *reinterpret_cast<const bf16x8*>(&Bs[r * 32 + ((q ^ swz(r)) << 3)]);
    }
#pragma unroll
    for (int mi = 0; mi < 2; ++mi)
#pragma unroll
      for (int oi = 0; oi < 4; ++oi)
        acc[mi][oi] = __builtin_amdgcn_mfma_f32_16x16x32_bf16(af[mi], bfr[oi], acc[mi][oi], 0, 0, 0);
    __syncthreads();
  }
#pragma unroll
  for (int mi = 0; mi < 2; ++mi)
#pragma unroll
    for (int oi = 0; oi < 4; ++oi) {
      int o = wc * 64 + oi * 16 + (lane & 15);
      int mb = m0 + wr * 32 + mi * 16 + ((lane >> 4) << 2);
#pragma unroll
      for (int j = 0; j < 4; ++j)
        Y[(size_t)(mbase + mb + j) * O_ + o] = acc[mi][oi][j];
    }
}

// ---------------------------------------------------------------------------
__global__ __launch_bounds__(256) void bn_stats_kernel(const float* __restrict__ Y,
                                                       float* __restrict__ stats) {
  int o = threadIdx.x & 127;
  int seg = blockIdx.x * 2 + (threadIdx.x >> 7);   // 512 segs x 72 rows
  const float* p = Y + (size_t)seg * 72 * O_ + o;
  float s = 0.f, s2 = 0.f;
#pragma unroll 4
  for (int mm = 0; mm < 72; ++mm) {
    float v = p[(size_t)mm * O_];
    s += v; s2 += v * v;
  }
  atomicAdd(&stats[o], s);
  atomicAdd(&stats[128 + o], s2);
}

// BN+ReLU elementwise, Y[m][o] fp32 -> padded NHWC bf16 hp (interior)
__global__ __launch_bounds__(256) void bn_apply_pad_kernel(
    const float* __restrict__ Y, const float* __restrict__ stats,
    const float* __restrict__ gamma, const float* __restrict__ beta,
    ushort_t* __restrict__ hp) {
  int g = blockIdx.x * 256 + threadIdx.x;    // NHW*16
  int m = g >> 4;
  int o0 = (g & 15) * 8;
  int n = m / HW, hw = m % HW;
  int y = hw / W_, x = hw % W_;
  const float4* yp = reinterpret_cast<const float4*>(Y) + (size_t)g * 2;
  float4 a = yp[0], b = yp[1];
  float va[8] = {a.x, a.y, a.z, a.w, b.x, b.y, b.z, b.w};
  u16x8 r;
#pragma unroll
  for (int e = 0; e < 8; ++e) {
    int o = o0 + e;
    float mu = stats[o] * (1.f / (float)NHW);
    float var = stats[128 + o] * (1.f / (float)NHW) - mu * mu;
    float sc = rsqrtf(var + 1e-5f) * gamma[o];
    float sh = beta[o] - mu * sc;
    r[e] = f2bf(fmaxf(fmaf(va[e], sc, sh), 0.f));
  }
  size_t pp = ((size_t)n * PHW + (y + 1) * PW + (x + 1)) * 128;
  *reinterpret_cast<u16x8*>(hp + pp + o0) = r;
}

// BN apply + ReLU, transposing [m][o] -> [n][o][hw] fp32 (final output)
__global__ __launch_bounds__(256) void bn_apply_t_kernel(
    const float* __restrict__ Y, const float* __restrict__ stats,
    const float* __restrict__ gamma, const float* __restrict__ beta,
    float* __restrict__ outf) {
  __shared__ float L[64][129];
  __shared__ float Lsc[128], Lsh[128];
  int tid = threadIdx.x;
  int m0 = blockIdx.x * 64;
  if (tid < 128) {
    float mu = stats[tid] * (1.f / (float)NHW);
    float var = stats[128 + tid] * (1.f / (float)NHW) - mu * mu;
    float sc = rsqrtf(var + 1e-5f) * gamma[tid];
    Lsc[tid] = sc;
    Lsh[tid] = beta[tid] - mu * sc;
  }
#pragma unroll
  for (int it = 0; it < 8; ++it) {
    int idx = it * 256 + tid;
    int ml = idx >> 5, oq = idx & 31;
    float4 v = *reinterpret_cast<const float4*>(&Y[(size_t)(m0 + ml) * O_ + oq * 4]);
    L[ml][oq * 4 + 0] = v.x; L[ml][oq * 4 + 1] = v.y;
    L[ml][oq * 4 + 2] = v.z; L[ml][oq * 4 + 3] = v.w;
  }
  __syncthreads();
  int n = m0 / HW, hw0 = m0 % HW;
#pragma unroll
  for (int it = 0; it < 32; ++it) {
    int idx = it * 256 + tid;
    int ol = idx >> 6, ml = idx & 63;
    float r = fmaxf(fmaf(L[ml][ol], Lsc[ol], Lsh[ol]), 0.f);
    outf[((size_t)n * O_ + ol) * HW + hw0 + ml] = r;
  }
}

// ---------------------------------------------------------------------------
extern "C" void kernel_launch(void* const* d_in, const int* in_sizes, int n_in,
                              void* d_out, int out_size, void* d_ws, size_t ws_size,
                              hipStream_t stream) {
  const float* x      = (const float*)d_in[0];
  const float* w1     = (const float*)d_in[1];
  const float* off_w1 = (const float*)d_in[2];
  const float* off_b1 = (const float*)d_in[3];
  const float* gamma1 = (const float*)d_in[4];
  const float* beta1  = (const float*)d_in[5];
  const float* w2     = (const float*)d_in[6];
  const float* off_w2 = (const float*)d_in[7];
  const float* off_b2 = (const float*)d_in[8];
  const float* gamma2 = (const float*)d_in[9];
  const float* beta2  = (const float*)d_in[10];
  float* out = (float*)d_out;

  char* p = (char*)d_ws;
  auto alloc = [&](size_t bytes) -> void* {
    void* r = (void*)p;
    p += (bytes + 255) & ~(size_t)255;
    return r;
  };
  float*    offt  = (float*)alloc((size_t)NHW * 28 * 4);            // 4.13 MB
  float*    Y     = (float*)alloc((size_t)NHW * O_ * 4);            // 18.9 MB
  float*    stats = (float*)alloc(512 * 4);
  ushort_t* wB1   = (ushort_t*)alloc(73728 * 2);
  ushort_t* wB2   = (ushort_t*)alloc(147456 * 2);
  ushort_t* wOB1  = (ushort_t*)alloc(32 * 576 * 2);
  ushort_t* wOB2  = (ushort_t*)alloc(32 * 1152 * 2);
  ushort_t* xp    = (ushort_t*)alloc((size_t)N_ * PHW * 64 * 2);    // 4.92 MB
  ushort_t* hp    = (ushort_t*)alloc((size_t)N_ * PHW * 128 * 2);   // 9.84 MB
  size_t used = (size_t)(p - (char*)d_ws);
  size_t s_full = (size_t)NHW * 1152 * 2;                           // 84.9 MB
  int nspan = (ws_size >= used + s_full) ? 4 : 1;                   // chunk if tight
  ushort_t* sbuf = (ushort_t*)p;

  // prep: zero padded buffers (borders must be 0 every launch), weights
  hipMemsetAsync(xp, 0, (size_t)N_ * PHW * 64 * 2, stream);
  hipMemsetAsync(hp, 0, (size_t)N_ * PHW * 128 * 2, stream);
  hipMemsetAsync(stats, 0, 512 * 4, stream);
  to_nhwc_pad_kernel<<<2304, 256, 0, stream>>>(x, xp, 64);
  transpose_w_kernel<<<288, 256, 0, stream>>>(w1, wB1, 64);
  transpose_w_kernel<<<576, 256, 0, stream>>>(w2, wB2, 128);
  transpose_wo_kernel<<<72, 256, 0, stream>>>(off_w1, wOB1, 64);
  transpose_wo_kernel<<<144, 256, 0, stream>>>(off_w2, wOB2, 128);

  // ---- layer 1 (C=64, K=576) ----
  for (int n0 = 0; n0 < 4; n0 += nspan) {
    gemm_off_kernel<64><<<nspan * 144, 256, 0, stream>>>(xp, wOB1, off_b1, offt, n0);
    sample_nhwc_kernel<64><<<nspan * 2592, 256, 0, stream>>>(xp, offt, sbuf, n0);
    gemm_kernel<576><<<nspan * 144, 256, 0, stream>>>(sbuf, wB1, Y, n0 * HW);
  }
  bn_stats_kernel<<<256, 256, 0, stream>>>(Y, stats);
  bn_apply_pad_kernel<<<2304, 256, 0, stream>>>(Y, stats, gamma1, beta1, hp);

  // ---- layer 2 (C=128, K=1152) ----
  for (int n0 = 0; n0 < 4; n0 += nspan) {
    gemm_off_kernel<128><<<nspan * 144, 256, 0, stream>>>(hp, wOB2, off_b2, offt, n0);
    sample_nhwc_kernel<128><<<nspan * 5184, 256, 0, stream>>>(hp, offt, sbuf, n0);
    gemm_kernel<1152><<<nspan * 144, 256, 0, stream>>>(sbuf, wB2, Y, n0 * HW);
  }
  bn_stats_kernel<<<256, 256, 0, stream>>>(Y, stats + 256);
  bn_apply_t_kernel<<<576, 256, 0, stream>>>(Y, stats + 256, gamma2, beta2, out);
}